// Round 5
// baseline (266.346 us; speedup 1.0000x reference)
//
#include <hip/hip_runtime.h>

// Problem constants
#define BATCH   4
#define SEQ     2048
#define DMODEL  1024
#define NHEADS  16
#define HDIM    64
// SCALE * log2(e) folded into Q at the GEMM epilogue: exp(s*0.125) = exp2(s*QSC)
#define QSC     0.18033688f

typedef short s16x8 __attribute__((ext_vector_type(8)));
typedef float f32x4 __attribute__((ext_vector_type(4)));
typedef const __attribute__((address_space(1))) unsigned int* gas_t;
typedef __attribute__((address_space(3))) unsigned int* las_t;

__device__ inline unsigned short f2bf(float f) {
    unsigned int u = __float_as_uint(f);
    u += 0x7FFF + ((u >> 16) & 1);   // RNE
    return (unsigned short)(u >> 16);
}

__device__ __forceinline__ float exp2_fast(float x) {
#if __has_builtin(__builtin_amdgcn_exp2f)
    return __builtin_amdgcn_exp2f(x);
#else
    return exp2f(x);
#endif
}

__device__ __forceinline__ float rcp_fast(float x) {
#if __has_builtin(__builtin_amdgcn_rcpf)
    return __builtin_amdgcn_rcpf(x);
#else
    return 1.0f / x;
#endif
}

// pack two positive floats to bf16x2 (round-half-up), lo in low 16 bits
__device__ __forceinline__ unsigned int pack_bf16x2(float lo, float hi) {
    unsigned int a = __float_as_uint(lo) + 0x8000u;
    unsigned int b = __float_as_uint(hi) + 0x8000u;
#if __has_builtin(__builtin_amdgcn_perm)
    return __builtin_amdgcn_perm(b, a, 0x07060302u);
#else
    return (a >> 16) | (b & 0xFFFF0000u);
#endif
}

// ---------------- fp32 -> bf16 convert (4 elems/thread) ----------------
__global__ void cvt_bf16(const float* __restrict__ in,
                         unsigned short* __restrict__ out, int n4) {
    int i = blockIdx.x * blockDim.x + threadIdx.x;
    if (i >= n4) return;
    float4 v = ((const float4*)in)[i];
    ushort4 o;
    o.x = f2bf(v.x); o.y = f2bf(v.y); o.z = f2bf(v.z); o.w = f2bf(v.w);
    ((ushort4*)out)[i] = o;
}

// ---------------- QKV projection GEMM ----------------
// C[m,o] = sum_k Xb[m,k] * Wb[o,k]   (M=8192, N=3072, K=1024)
// Double-buffered LDS + VGPR prefetch, 1 barrier per K-step.
__global__ __launch_bounds__(256, 4) void qkv_gemm(
    const unsigned short* __restrict__ Xb,
    const unsigned short* __restrict__ Wb,
    unsigned short* __restrict__ Qo,
    unsigned short* __restrict__ Ko,
    unsigned short* __restrict__ Vt)
{
    __shared__ __align__(16) unsigned short As[2][128 * 32];
    __shared__ __align__(16) unsigned short Bs[2][128 * 32];

    const int t    = threadIdx.x;
    const int m0   = blockIdx.y * 128;
    const int n0   = blockIdx.x * 128;
    const int wid  = t >> 6;
    const int lane = t & 63;
    const int l15  = lane & 15;
    const int quad = lane >> 4;
    const int wm   = (wid >> 1) * 64;
    const int wn   = (wid & 1) * 64;

    // staging: 2 threads per row, 16 elems (32B) each
    const int srow = t >> 1;
    const int koff = (t & 1) * 16;

    const unsigned short* gA = &Xb[(size_t)(m0 + srow) * 1024 + koff];
    const unsigned short* gB = &Wb[(size_t)(n0 + srow) * 1024 + koff];

    f32x4 acc[4][4] = {};
    uint4 ra0, ra1, rb0, rb1;

    auto gload = [&](int k0) {
        const uint4* pa = (const uint4*)(gA + k0);
        ra0 = pa[0]; ra1 = pa[1];
        const uint4* pb = (const uint4*)(gB + k0);
        rb0 = pb[0]; rb1 = pb[1];
    };
    auto swrite = [&](int buf) {
        uint4* sa = (uint4*)&As[buf][srow * 32 + koff];
        sa[0] = ra0; sa[1] = ra1;
        uint4* sb = (uint4*)&Bs[buf][srow * 32 + koff];
        sb[0] = rb0; sb[1] = rb1;
    };

    gload(0);
    swrite(0);
    __syncthreads();

    int cur = 0;
    #pragma unroll 1
    for (int k0 = 0; k0 < 1024; k0 += 32) {
        const bool more = (k0 + 32) < 1024;
        if (more) gload(k0 + 32);

        s16x8 af[4], bf[4];
        #pragma unroll
        for (int mt = 0; mt < 4; mt++)
            af[mt] = *(const s16x8*)&As[cur][(wm + mt * 16 + l15) * 32 + quad * 8];
        #pragma unroll
        for (int nt = 0; nt < 4; nt++)
            bf[nt] = *(const s16x8*)&Bs[cur][(wn + nt * 16 + l15) * 32 + quad * 8];
        #pragma unroll
        for (int mt = 0; mt < 4; mt++)
            #pragma unroll
            for (int nt = 0; nt < 4; nt++)
                acc[mt][nt] = __builtin_amdgcn_mfma_f32_16x16x32_bf16(
                    af[mt], bf[nt], acc[mt][nt], 0, 0, 0);

        if (more) swrite(cur ^ 1);
        __syncthreads();
        cur ^= 1;
    }

    // epilogue (R1 form): C/D layout col=l15, row=quad*4+r
    #pragma unroll
    for (int mt = 0; mt < 4; mt++) {
        const int mbase = m0 + wm + mt * 16 + quad * 4;
        #pragma unroll
        for (int nt = 0; nt < 4; nt++) {
            const int o  = n0 + wn + nt * 16 + l15;
            const int p  = o >> 10;
            const int oo = o & 1023;
            const int h  = oo >> 6;
            const int d  = oo & 63;
            #pragma unroll
            for (int r = 0; r < 4; r++) {
                const int mm = mbase + r;
                const int b  = mm >> 11;
                const int n  = mm & 2047;
                float v = acc[mt][nt][r];
                if (p == 0)
                    Qo[((size_t)(b * 16 + h) * 2048 + n) * 64 + d] = f2bf(v * QSC);
                else if (p == 1)
                    Ko[((size_t)(b * 16 + h) * 2048 + n) * 64 + d] = f2bf(v);
                else
                    Vt[((size_t)(b * 16 + h) * 64 + d) * 2048 + n] = f2bf(v);
            }
        }
    }
}

// ---------------- fused attention ----------------
// Single-buffered K/V in LDS via global_load_lds; the DMA for tile t+1 is
// issued after a barrier confirming all waves consumed tile t, and overlaps
// the (per-wave, barrier-free) exp+PV phase. 34.8 KB LDS -> 4 blocks/CU,
// all co-resident (grid = 4 blocks/CU exactly).
// LDS map (ushort elems): K@0 (4096), V@4096 (4096), P@8192 + w*2304.
#define PSTRIDE 72
#define PBASE   8192

__global__ __launch_bounds__(256, 4) void attn(
    const unsigned short* __restrict__ Q,
    const unsigned short* __restrict__ K,
    const unsigned short* __restrict__ Vt,
    float* __restrict__ out)
{
    __shared__ __align__(16) unsigned short LDS[PBASE + 4 * 32 * PSTRIDE];

    const int t    = threadIdx.x;
    const int w    = t >> 6;
    const int lane = t & 63;
    const int l15  = lane & 15;
    const int quad = lane >> 4;
    const int head = blockIdx.y;            // b*16 + h
    const int b    = head >> 4;
    const int h    = head & 15;
    const int q0   = blockIdx.x * 128 + w * 32;

    const unsigned short* Qh = Q  + (size_t)head * 2048 * 64;
    const unsigned short* Kh = K  + (size_t)head * 2048 * 64;
    const unsigned short* Vh = Vt + (size_t)head * 64 * 2048;

    // staging source addresses: phys chunk i = rd*256 + t holds logical
    // (row = i>>3, col = (i&7) ^ (row&7)); DMA dst is lane-linear.
    const int r0 = t >> 3;
    const int c0 = (t & 7) ^ (r0 & 7);
    const unsigned short* srcK = Kh + r0 * 64 + c0 * 8;
    const unsigned short* srcV = Vh + r0 * 2048 + c0 * 8;

    auto stage = [&](int kt) {
        #pragma unroll
        for (int rd = 0; rd < 2; rd++) {
            __builtin_amdgcn_global_load_lds(
                (gas_t)(const void*)(srcK + kt * 4096 + rd * 2048),
                (las_t)(void*)&LDS[rd * 2048 + w * 512], 16, 0, 0);
            __builtin_amdgcn_global_load_lds(
                (gas_t)(const void*)(srcV + kt * 64 + rd * 65536),
                (las_t)(void*)&LDS[4096 + rd * 2048 + w * 512], 16, 0, 0);
        }
    };

    // Q fragments (pre-scaled by QSC in gemm), B-operand role
    s16x8 qb[2][2];
    #pragma unroll
    for (int mt = 0; mt < 2; mt++)
        #pragma unroll
        for (int kc = 0; kc < 2; kc++)
            qb[mt][kc] = *(const s16x8*)&Qh[(size_t)(q0 + mt * 16 + l15) * 64 + kc * 32 + quad * 8];

    f32x4 y[2][4] = {};
    float lsum[2] = {0.f, 0.f};
    unsigned short* P = &LDS[PBASE + w * (32 * PSTRIDE)];

    // swizzled in-tile column offsets (elems) for kc=0/1
    const int x7   = l15 & 7;
    const int csw0 = (quad ^ x7) * 8;
    const int csw1 = ((4 + quad) ^ x7) * 8;

    stage(0);
    __syncthreads();

    #pragma unroll 1
    for (int kt = 0; kt < 32; kt++) {
        // K fragments + QK MFMAs (kb dead after this block)
        s16x8 kb[4][2];
        #pragma unroll
        for (int nt = 0; nt < 4; nt++) {
            const int rowb = (nt * 16 + l15) * 64;
            kb[nt][0] = *(const s16x8*)&LDS[rowb + csw0];
            kb[nt][1] = *(const s16x8*)&LDS[rowb + csw1];
        }
        f32x4 st[4][2] = {};
        #pragma unroll
        for (int kc = 0; kc < 2; kc++)
            #pragma unroll
            for (int nt = 0; nt < 4; nt++)
                #pragma unroll
                for (int mt = 0; mt < 2; mt++)
                    st[nt][mt] = __builtin_amdgcn_mfma_f32_16x16x32_bf16(
                        kb[nt][kc], qb[mt][kc], st[nt][mt], 0, 0, 0);

        // V fragments into registers (live across the stage barrier)
        s16x8 vb[4][2];
        #pragma unroll
        for (int dt = 0; dt < 4; dt++) {
            const int rowb = 4096 + (dt * 16 + l15) * 64;
            vb[dt][0] = *(const s16x8*)&LDS[rowb + csw0];
            vb[dt][1] = *(const s16x8*)&LDS[rowb + csw1];
        }

        __syncthreads();                 // all KV reads of tile kt complete
        if (kt + 1 < 32) stage(kt + 1);  // DMA overlaps exp+PV below

        // exp2 + pack + ds_write_b64 into per-wave P region
        #pragma unroll
        for (int mt = 0; mt < 2; mt++)
            #pragma unroll
            for (int nt = 0; nt < 4; nt++) {
                float p0 = exp2_fast(st[nt][mt][0]);
                float p1 = exp2_fast(st[nt][mt][1]);
                float p2 = exp2_fast(st[nt][mt][2]);
                float p3 = exp2_fast(st[nt][mt][3]);
                lsum[mt] += (p0 + p1) + (p2 + p3);
                uint2 u;
                u.x = pack_bf16x2(p0, p1);
                u.y = pack_bf16x2(p2, p3);
                *(uint2*)&P[(mt * 16 + l15) * PSTRIDE + nt * 16 + quad * 4] = u;
            }
        // Y += P V
        #pragma unroll
        for (int kc = 0; kc < 2; kc++) {
            s16x8 pa[2];
            #pragma unroll
            for (int mt = 0; mt < 2; mt++)
                pa[mt] = *(const s16x8*)&P[(mt * 16 + l15) * PSTRIDE + kc * 32 + quad * 8];
            #pragma unroll
            for (int mt = 0; mt < 2; mt++)
                #pragma unroll
                for (int dt = 0; dt < 4; dt++)
                    y[mt][dt] = __builtin_amdgcn_mfma_f32_16x16x32_bf16(
                        pa[mt], vb[dt][kc], y[mt][dt], 0, 0, 0);
        }

        __syncthreads();                 // DMA drained: tile kt+1 ready
    }

    // reduce lsum across quads (lanes sharing l15 hold disjoint n-subsets)
    #pragma unroll
    for (int mt = 0; mt < 2; mt++) {
        float v = lsum[mt];
        v += __shfl_xor(v, 16);
        v += __shfl_xor(v, 32);
        lsum[mt] = v;
    }

    float rinv[2][4];
    #pragma unroll
    for (int mt = 0; mt < 2; mt++)
        #pragma unroll
        for (int r = 0; r < 4; r++)
            rinv[mt][r] = rcp_fast(__shfl(lsum[mt], quad * 4 + r));

    // out[b, n, h*64+d] fp32; C-layout: col=l15 -> d, row=quad*4+r -> m
    #pragma unroll
    for (int mt = 0; mt < 2; mt++)
        #pragma unroll
        for (int dt = 0; dt < 4; dt++)
            #pragma unroll
            for (int r = 0; r < 4; r++) {
                const int n = q0 + mt * 16 + quad * 4 + r;
                const int d = dt * 16 + l15;
                out[((size_t)(b * 2048 + n)) * 1024 + h * 64 + d] =
                    y[mt][dt][r] * rinv[mt][r];
            }
}

// ---------------- launch ----------------
extern "C" void kernel_launch(void* const* d_in, const int* in_sizes, int n_in,
                              void* d_out, int out_size, void* d_ws, size_t ws_size,
                              hipStream_t stream) {
    const float* X = (const float*)d_in[0];   // [4,2048,1024]
    const float* W = (const float*)d_in[1];   // [3072,1024]
    float* out = (float*)d_out;

    char* ws = (char*)d_ws;
    unsigned short* Xb = (unsigned short*)(ws);                 // 16.8 MB
    unsigned short* Wb = (unsigned short*)(ws + 16777216);      //  6.3 MB
    unsigned short* Qb = (unsigned short*)(ws + 23068672);      // 16.8 MB
    unsigned short* Kb = (unsigned short*)(ws + 39845888);      // 16.8 MB
    unsigned short* Vt = (unsigned short*)(ws + 56623104);      // 16.8 MB (ends 73.4 MB)

    cvt_bf16<<<dim3(8192), dim3(256), 0, stream>>>(X, Xb, 2097152);
    cvt_bf16<<<dim3(3072), dim3(256), 0, stream>>>(W, Wb, 786432);
    qkv_gemm<<<dim3(24, 64), dim3(256), 0, stream>>>(Xb, Wb, Qb, Kb, Vt);
    attn<<<dim3(16, 64), dim3(256), 0, stream>>>(Qb, Kb, Vt, out);
}